// Round 2
// baseline (1239.609 us; speedup 1.0000x reference)
//
#include <hip/hip_runtime.h>
#include <math.h>

typedef _Float16 h8 __attribute__((ext_vector_type(8)));
typedef _Float16 h4 __attribute__((ext_vector_type(4)));
typedef float    f4 __attribute__((ext_vector_type(4)));

#define NQ    1024
#define HWK   4096
#define DM    512
#define NH    8
#define DKH   64

// load 8 consecutive fp32 and convert to f16 vector (for MFMA operand)
__device__ inline h8 cvt_h8(const float* __restrict__ p) {
    const f4* q = (const f4*)p;
    f4 a = q[0], b = q[1];
    h8 r;
    r[0] = (_Float16)a[0]; r[1] = (_Float16)a[1];
    r[2] = (_Float16)a[2]; r[3] = (_Float16)a[3];
    r[4] = (_Float16)b[0]; r[5] = (_Float16)b[1];
    r[6] = (_Float16)b[2]; r[7] = (_Float16)b[3];
    return r;
}

// ---------------------------------------------------------------------------
// mask[n][hw] (f16, 0 or -inf). Fully coalesced, no LDS.
// ---------------------------------------------------------------------------
__global__ __launch_bounds__(256)
void mask_kernel(const float* __restrict__ x_tilde, const float* __restrict__ x_hat,
                 _Float16* __restrict__ mask)
{
    int hw = blockIdx.x * 256 + threadIdx.x;
    int n  = blockIdx.y;
    float xt0 = x_tilde[hw * 2 + 0];
    float xt1 = x_tilde[hw * 2 + 1];
    size_t idx = ((size_t)n * HWK + hw) * 2;
    float dx = xt0 - x_hat[idx + 0];
    float dy = xt1 - x_hat[idx + 1];
    // forbid fma-contraction so the boundary matches the reference bit-for-bit
    float d2 = __fadd_rn(__fmul_rn(dx, dx), __fmul_rn(dy, dy));
    float dist = __fsqrt_rn(d2);
    mask[(size_t)n * HWK + hw] = (dist < 0.1f) ? (_Float16)0.0f
                                               : (_Float16)(-__builtin_inff());
}

// ---------------------------------------------------------------------------
// Q/K projection: C = X[M,512] @ W[512,512]^T + b, scaled, stored f16 as
// out[((b*NH+h) << nlog2) + n][dk], with m = (b << nlog2) + n, col = h*64+dk.
// ---------------------------------------------------------------------------
__global__ __launch_bounds__(256)
void proj_qk(const float* __restrict__ X, const float* __restrict__ W,
             const float* __restrict__ bias, _Float16* __restrict__ out,
             int nlog2, float scale)
{
    int tid = threadIdx.x;
    int w = tid >> 6, lane = tid & 63, q = lane >> 4, c = lane & 15;
    int wr = blockIdx.x * 128 + (w >> 1) * 64;
    int wc = blockIdx.y * 128 + (w & 1) * 64;

    f4 acc[4][4];
    const f4 fz = {0.f, 0.f, 0.f, 0.f};
#pragma unroll
    for (int i = 0; i < 4; i++)
#pragma unroll
        for (int j = 0; j < 4; j++) acc[i][j] = fz;

    for (int k0 = 0; k0 < DM; k0 += 32) {
        h8 af[4], bf[4];
#pragma unroll
        for (int i = 0; i < 4; i++)
            af[i] = cvt_h8(X + (size_t)(wr + i * 16 + c) * DM + k0 + q * 8);
#pragma unroll
        for (int j = 0; j < 4; j++)
            bf[j] = cvt_h8(W + (size_t)(wc + j * 16 + c) * DM + k0 + q * 8);
#pragma unroll
        for (int i = 0; i < 4; i++)
#pragma unroll
            for (int j = 0; j < 4; j++)
                acc[i][j] = __builtin_amdgcn_mfma_f32_16x16x32_f16(af[i], bf[j], acc[i][j], 0, 0, 0);
    }

    int nmask = (1 << nlog2) - 1;
#pragma unroll
    for (int j = 0; j < 4; j++) {
        int ncol = wc + j * 16 + c;
        float bb = bias[ncol];
        int hh = ncol >> 6, dk = ncol & 63;
#pragma unroll
        for (int i = 0; i < 4; i++) {
#pragma unroll
            for (int r = 0; r < 4; r++) {
                int m = wr + i * 16 + q * 4 + r;
                int b = m >> nlog2, n = m & nmask;
                float v = (acc[i][j][r] + bb) * scale;
                out[((((size_t)(b * NH + hh)) << nlog2) + n) * DKH + dk] = (_Float16)v;
            }
        }
    }
}

// ---------------------------------------------------------------------------
// V projection, transposed output: Vt[b,h,dk,m]
// ---------------------------------------------------------------------------
__global__ __launch_bounds__(256)
void proj_v(const float* __restrict__ V, const float* __restrict__ W,
            const float* __restrict__ bias, _Float16* __restrict__ out)
{
    int tid = threadIdx.x;
    int w = tid >> 6, lane = tid & 63, q = lane >> 4, c = lane & 15;
    int wr = blockIdx.x * 128 + (w >> 1) * 64;   // feature
    int wc = blockIdx.y * 128 + (w & 1) * 64;    // flat hw

    f4 acc[4][4];
    const f4 fz = {0.f, 0.f, 0.f, 0.f};
#pragma unroll
    for (int i = 0; i < 4; i++)
#pragma unroll
        for (int j = 0; j < 4; j++) acc[i][j] = fz;

    for (int k0 = 0; k0 < DM; k0 += 32) {
        h8 af[4], bf[4];
#pragma unroll
        for (int i = 0; i < 4; i++)
            af[i] = cvt_h8(W + (size_t)(wr + i * 16 + c) * DM + k0 + q * 8);
#pragma unroll
        for (int j = 0; j < 4; j++)
            bf[j] = cvt_h8(V + (size_t)(wc + j * 16 + c) * DM + k0 + q * 8);
#pragma unroll
        for (int i = 0; i < 4; i++)
#pragma unroll
            for (int j = 0; j < 4; j++)
                acc[i][j] = __builtin_amdgcn_mfma_f32_16x16x32_f16(af[i], bf[j], acc[i][j], 0, 0, 0);
    }

#pragma unroll
    for (int i = 0; i < 4; i++) {
#pragma unroll
        for (int r = 0; r < 4; r++) {
            int f = wr + i * 16 + q * 4 + r;     // feature row
            float bb = bias[f];
            int hh = f >> 6, dk = f & 63;
#pragma unroll
            for (int j = 0; j < 4; j++) {
                int col = wc + j * 16 + c;       // flat hw
                int b = col >> 12, hw = col & 4095;
                out[((size_t)(b * NH + hh) * DKH + dk) * HWK + hw] =
                    (_Float16)(acc[i][j][r] + bb);
            }
        }
    }
}

// ---------------------------------------------------------------------------
// out = ctx_h[4096,512] (f16) @ Wo^T + bo  -> fp32
// ---------------------------------------------------------------------------
__global__ __launch_bounds__(256)
void proj_o(const _Float16* __restrict__ C, const float* __restrict__ W,
            const float* __restrict__ bias, float* __restrict__ out)
{
    int tid = threadIdx.x;
    int w = tid >> 6, lane = tid & 63, q = lane >> 4, c = lane & 15;
    int wr = blockIdx.x * 128 + (w >> 1) * 64;
    int wc = blockIdx.y * 128 + (w & 1) * 64;

    f4 acc[4][4];
    const f4 fz = {0.f, 0.f, 0.f, 0.f};
#pragma unroll
    for (int i = 0; i < 4; i++)
#pragma unroll
        for (int j = 0; j < 4; j++) acc[i][j] = fz;

    for (int k0 = 0; k0 < DM; k0 += 32) {
        h8 af[4], bf[4];
#pragma unroll
        for (int i = 0; i < 4; i++)
            af[i] = *(const h8*)(C + (size_t)(wr + i * 16 + c) * DM + k0 + q * 8);
#pragma unroll
        for (int j = 0; j < 4; j++)
            bf[j] = cvt_h8(W + (size_t)(wc + j * 16 + c) * DM + k0 + q * 8);
#pragma unroll
        for (int i = 0; i < 4; i++)
#pragma unroll
            for (int j = 0; j < 4; j++)
                acc[i][j] = __builtin_amdgcn_mfma_f32_16x16x32_f16(af[i], bf[j], acc[i][j], 0, 0, 0);
    }

#pragma unroll
    for (int j = 0; j < 4; j++) {
        int ncol = wc + j * 16 + c;
        float bb = bias[ncol];
#pragma unroll
        for (int i = 0; i < 4; i++) {
#pragma unroll
            for (int r = 0; r < 4; r++) {
                int m = wr + i * 16 + q * 4 + r;
                out[(size_t)m * DM + ncol] = acc[i][j][r] + bb;
            }
        }
    }
}

// ---------------------------------------------------------------------------
// Attention scores: S^T tiles (A=K rows m, B=Q rows n) -> C row=m, col=n.
// Each lane holds 4 consecutive m of one n: exp -> h4 -> direct global store
// to eBuf[bh][n][m] (f16, unnormalized). Row sums -> global atomicAdd.
// Grid: bh(32) x ntile(16, 64 rows) x mtile(4, 1024 m). No LDS in hot loop.
// ---------------------------------------------------------------------------
__global__ __launch_bounds__(256)
void attn_scores(const _Float16* __restrict__ Qh, const _Float16* __restrict__ Kh,
                 const _Float16* __restrict__ mask,
                 _Float16* __restrict__ eBuf, float* __restrict__ lsum_g)
{
    __shared__ float red[4][64];
    int tid = threadIdx.x;
    int w = tid >> 6, lane = tid & 63, q = lane >> 4, c = lane & 15;
    int bx = blockIdx.x;
    int mt = bx & 3, nt = (bx >> 2) & 15, bh = bx >> 6;
    int n0 = nt * 64;

    const _Float16* Qb = Qh + ((size_t)bh * NQ + n0) * DKH;
    const _Float16* Kb = Kh + (size_t)bh * HWK * DKH;
    _Float16* eb = eBuf + (size_t)bh * NQ * HWK;

    // Q fragments (B-operand, rows n), held for the kernel
    h8 qb[4][2];
#pragma unroll
    for (int j = 0; j < 4; j++)
#pragma unroll
        for (int ks = 0; ks < 2; ks++)
            qb[j][ks] = *(const h8*)(Qb + (size_t)(j * 16 + c) * DKH + ks * 32 + q * 8);

    float lsum[4] = {0.f, 0.f, 0.f, 0.f};

    for (int it = 0; it < 4; ++it) {
        int m0 = mt * 1024 + w * 256 + it * 64;
        h8 ka[4][2];
#pragma unroll
        for (int i = 0; i < 4; i++)
#pragma unroll
            for (int ks = 0; ks < 2; ks++)
                ka[i][ks] = *(const h8*)(Kb + (size_t)(m0 + i * 16 + c) * DKH + ks * 32 + q * 8);

#pragma unroll
        for (int i = 0; i < 4; i++) {
#pragma unroll
            for (int j = 0; j < 4; j++) {
                f4 acc = {0.f, 0.f, 0.f, 0.f};
                acc = __builtin_amdgcn_mfma_f32_16x16x32_f16(ka[i][0], qb[j][0], acc, 0, 0, 0);
                acc = __builtin_amdgcn_mfma_f32_16x16x32_f16(ka[i][1], qb[j][1], acc, 0, 0, 0);
                size_t roff = (size_t)(n0 + j * 16 + c) * HWK + m0 + i * 16 + q * 4;
                h4 mk = *(const h4*)(mask + roff);
                h4 ev;
#pragma unroll
                for (int r = 0; r < 4; r++) {
                    float e = __expf(acc[r] + (float)mk[r]);
                    lsum[j] += e;
                    ev[r] = (_Float16)e;
                }
                *(h4*)(eb + roff) = ev;
            }
        }
    }

    // full row sum for n = j*16+c: add the 4 q-lane partials
#pragma unroll
    for (int j = 0; j < 4; j++) {
        float s = lsum[j];
        s += __shfl_xor(s, 16);
        s += __shfl_xor(s, 32);
        if (q == 0) red[w][j * 16 + c] = s;
    }
    __syncthreads();
    if (tid < 64)
        atomicAdd(lsum_g + (size_t)bh * NQ + n0 + tid,
                  red[0][tid] + red[1][tid] + red[2][tid] + red[3][tid]);
}

// ---------------------------------------------------------------------------
// PV + normalize: eBuf is already in A-operand layout. PV MFMA + coalesced
// attn = e * invl fp32 stream-out. Grid: bh(32) x ntile(64, 16 rows) = 2048.
// Waves split m; small LDS ctx reduction.
// ---------------------------------------------------------------------------
__global__ __launch_bounds__(256)
void attn_pv(const _Float16* __restrict__ eBuf, const _Float16* __restrict__ Vt,
             const float* __restrict__ lsum_g,
             float* __restrict__ attn_out, _Float16* __restrict__ ctx_h)
{
    __shared__ float invS[16];
    __shared__ float Cr[16][68];

    int tid = threadIdx.x;
    int w = tid >> 6, lane = tid & 63, q = lane >> 4, c = lane & 15;
    int nt = blockIdx.x & 63, bh = blockIdx.x >> 6;
    int n0 = nt * 16;

    if (tid < 16) invS[tid] = 1.0f / lsum_g[(size_t)bh * NQ + n0 + tid];
    for (int idx = tid; idx < 16 * 68; idx += 256) (&Cr[0][0])[idx] = 0.f;
    __syncthreads();

    const _Float16* eb = eBuf + ((size_t)bh * NQ + n0) * HWK;
    const _Float16* Vb = Vt + (size_t)bh * DKH * HWK;
    float* ab = attn_out + ((size_t)bh * NQ + n0) * HWK;

    f4 cacc[4];
    const f4 fz = {0.f, 0.f, 0.f, 0.f};
#pragma unroll
    for (int jd = 0; jd < 4; jd++) cacc[jd] = fz;

    for (int it = 0; it < 16; ++it) {
        int m0 = it * 256 + w * 64;
        h8 pa[2];
#pragma unroll
        for (int ks = 0; ks < 2; ks++)
            pa[ks] = *(const h8*)(eb + (size_t)c * HWK + m0 + ks * 32 + q * 8);
        h8 vb[4][2];
#pragma unroll
        for (int jd = 0; jd < 4; jd++)
#pragma unroll
            for (int ks = 0; ks < 2; ks++)
                vb[jd][ks] = *(const h8*)(Vb + (size_t)(jd * 16 + c) * HWK + m0 + ks * 32 + q * 8);
#pragma unroll
        for (int jd = 0; jd < 4; jd++) {
            cacc[jd] = __builtin_amdgcn_mfma_f32_16x16x32_f16(pa[0], vb[jd][0], cacc[jd], 0, 0, 0);
            cacc[jd] = __builtin_amdgcn_mfma_f32_16x16x32_f16(pa[1], vb[jd][1], cacc[jd], 0, 0, 0);
        }
        // normalize + write 16 rows x 64 m fp32, coalesced 8x(128B read, 256B write)
#pragma unroll
        for (int s = 0; s < 2; s++) {
            int row = s * 8 + (lane >> 3);
            int mc = (lane & 7) * 8;
            h8 e8 = *(const h8*)(eb + (size_t)row * HWK + m0 + mc);
            float il = invS[row];
            f4 o0, o1;
            o0[0] = (float)e8[0] * il; o0[1] = (float)e8[1] * il;
            o0[2] = (float)e8[2] * il; o0[3] = (float)e8[3] * il;
            o1[0] = (float)e8[4] * il; o1[1] = (float)e8[5] * il;
            o1[2] = (float)e8[6] * il; o1[3] = (float)e8[7] * il;
            float* dst = ab + (size_t)row * HWK + m0 + mc;
            *(f4*)dst = o0;
            *(f4*)(dst + 4) = o1;
        }
    }

    // ctx reduction across the 4 m-split waves
#pragma unroll
    for (int jd = 0; jd < 4; jd++)
#pragma unroll
        for (int r = 0; r < 4; r++)
            atomicAdd(&Cr[q * 4 + r][jd * 16 + c], cacc[jd][r]);
    __syncthreads();

    int b = bh >> 3, h = bh & 7;
    _Float16* cb = ctx_h + ((size_t)b * NQ + n0) * DM + h * DKH;
#pragma unroll
    for (int g = 0; g < 4; g++) {
        int row = g * 4 + (tid >> 6);
        int col = tid & 63;
        cb[(size_t)row * DM + col] = (_Float16)(Cr[row][col] * invS[row]);
    }
}

// ---------------------------------------------------------------------------
extern "C" void kernel_launch(void* const* d_in, const int* in_sizes, int n_in,
                              void* d_out, int out_size, void* d_ws, size_t ws_size,
                              hipStream_t stream)
{
    const float* query   = (const float*)d_in[0];
    const float* key     = (const float*)d_in[1];
    const float* value   = (const float*)d_in[2];
    const float* x_tilde = (const float*)d_in[3];
    const float* x_hat   = (const float*)d_in[4];
    const float* Wq = (const float*)d_in[5];
    const float* bq = (const float*)d_in[6];
    const float* Wk = (const float*)d_in[7];
    const float* bk = (const float*)d_in[8];
    const float* Wv = (const float*)d_in[9];
    const float* bv = (const float*)d_in[10];
    const float* Wo = (const float*)d_in[11];
    const float* bo = (const float*)d_in[12];

    char* ws = (char*)d_ws;
    _Float16* Qh    = (_Float16*)(ws);                       //  4 MB [B,H,N,64]
    _Float16* Kh    = (_Float16*)(ws + ((size_t)4  << 20));  // 16 MB [B,H,HW,64]
    _Float16* Vt    = (_Float16*)(ws + ((size_t)20 << 20));  // 16 MB [B,H,64,HW]
    _Float16* ctxh  = (_Float16*)(ws + ((size_t)36 << 20));  //  4 MB [B,N,512]
    _Float16* mask  = (_Float16*)(ws + ((size_t)40 << 20));  //  8 MB [N,HW]
    float*    lsum  = (float*)   (ws + ((size_t)48 << 20));  // 128 KB [B,H,N]
    _Float16* eBuf  = (_Float16*)(ws + ((size_t)52 << 20));  // 256 MB [B,H,N,HW]

    float* out  = (float*)d_out;
    float* attn = out + (size_t)4 * NQ * DM;   // out [4,1024,512] then attn

    hipMemsetAsync(lsum, 0, (size_t)4 * NH * NQ * sizeof(float), stream);

    mask_kernel<<<dim3(HWK / 256, NQ), 256, 0, stream>>>(x_tilde, x_hat, mask);
    proj_qk<<<dim3(4 * NQ / 128, DM / 128), 256, 0, stream>>>(query, Wq, bq, Qh, 10, 0.125f);
    proj_qk<<<dim3(4 * HWK / 128, DM / 128), 256, 0, stream>>>(key, Wk, bk, Kh, 12, 1.0f);
    proj_v<<<dim3(DM / 128, 4 * HWK / 128), 256, 0, stream>>>(value, Wv, bv, Vt);
    attn_scores<<<32 * 16 * 4, 256, 0, stream>>>(Qh, Kh, mask, eBuf, lsum);
    attn_pv<<<32 * 64, 256, 0, stream>>>(eBuf, Vt, lsum, attn, ctxh);
    proj_o<<<dim3(4 * NQ / 128, DM / 128), 256, 0, stream>>>(ctxh, Wo, bo, out);
}